// Round 8
// baseline (113.604 us; speedup 1.0000x reference)
//
#include <hip/hip_runtime.h>

typedef __attribute__((ext_vector_type(8))) short bf16x8;
typedef __attribute__((ext_vector_type(4))) float f32x4;

// RNE bf16 (epilogues — off critical path)
__device__ __forceinline__ unsigned short f2bf(float f) {
    unsigned int u = __builtin_bit_cast(unsigned int, f);
    unsigned int r = (u + 0x7FFFu + ((u >> 16) & 1u)) >> 16;
    return (unsigned short)r;
}
// round-half-up pack of two fp32 -> packed bf16x2 (cheap) — staging hot path
__device__ __forceinline__ unsigned int pkbf(float lo, float hi) {
    unsigned int ul = __builtin_bit_cast(unsigned int, lo) + 0x8000u;
    unsigned int uh = __builtin_bit_cast(unsigned int, hi) + 0x8000u;
    return (uh & 0xFFFF0000u) | (ul >> 16);
}
__device__ __forceinline__ float bf2f(unsigned short u) {
    unsigned int x = ((unsigned int)u) << 16;
    return __builtin_bit_cast(float, x);
}

__device__ __forceinline__ void gll16(const void* g, void* l) {
    __builtin_amdgcn_global_load_lds(
        (const __attribute__((address_space(1))) void*)g,
        (__attribute__((address_space(3))) void*)l, 16, 0, 0);
}

// ---------------------------------------------------------------------------
// kW: tiled transpose + fp32->bf16. src [b][R][C] f32 -> dstT [b][C][R] bf16.
// ---------------------------------------------------------------------------
__global__ __launch_bounds__(256) void transpose_cvt_kernel(
    const float* __restrict__ src, unsigned short* __restrict__ dstT,
    unsigned short* __restrict__ dstS, int R, int C)
{
    __shared__ float tile[64][65];
    const int b = blockIdx.z;
    const float* s = src + (size_t)b * R * C;
    const int r0 = blockIdx.x * 64, c0 = blockIdx.y * 64;
    const int t = threadIdx.x;
    const int r = t >> 2, cg = (t & 3) * 16;

    float v[16];
    const float4* p = reinterpret_cast<const float4*>(s + (size_t)(r0 + r) * C + c0 + cg);
#pragma unroll
    for (int i = 0; i < 4; ++i) {
        float4 q = p[i];
        v[4 * i + 0] = q.x; v[4 * i + 1] = q.y; v[4 * i + 2] = q.z; v[4 * i + 3] = q.w;
    }
#pragma unroll
    for (int i = 0; i < 16; ++i) tile[r][cg + i] = v[i];

    if (dstS) {
        unsigned int w[8];
#pragma unroll
        for (int i = 0; i < 8; ++i)
            w[i] = (unsigned)f2bf(v[2 * i]) | ((unsigned)f2bf(v[2 * i + 1]) << 16);
        unsigned int* d = reinterpret_cast<unsigned int*>(
            dstS + (size_t)b * R * C + (size_t)(r0 + r) * C + c0 + cg);
        *reinterpret_cast<uint4*>(d)     = make_uint4(w[0], w[1], w[2], w[3]);
        *reinterpret_cast<uint4*>(d + 4) = make_uint4(w[4], w[5], w[6], w[7]);
    }

    __syncthreads();

    const int cl = t >> 2, rg = (t & 3) * 16;
    unsigned int w[8];
#pragma unroll
    for (int i = 0; i < 8; ++i) {
        unsigned short lo = f2bf(tile[rg + 2 * i][cl]);
        unsigned short hi = f2bf(tile[rg + 2 * i + 1][cl]);
        w[i] = (unsigned)lo | ((unsigned)hi << 16);
    }
    unsigned int* d = reinterpret_cast<unsigned int*>(
        dstT + (size_t)b * R * C + (size_t)(c0 + cl) * R + r0 + rg);
    *reinterpret_cast<uint4*>(d)     = make_uint4(w[0], w[1], w[2], w[3]);
    *reinterpret_cast<uint4*>(d + 4) = make_uint4(w[4], w[5], w[6], w[7]);
}

// ---------------------------------------------------------------------------
// kPre: H = F@W1 + bias (bf16 row-major) and G^T = (F@W2)^T (bf16
// [batch][256][2048]). Unchanged (passed; small).
// ---------------------------------------------------------------------------
__global__ __launch_bounds__(256, 2) void kpre_gemm(
    const float* __restrict__ F, const unsigned short* __restrict__ Wt,
    const float* __restrict__ bias, unsigned short* __restrict__ H,
    unsigned short* __restrict__ Gt)
{
    __shared__ __align__(16) short Fb[64 * 256];   // 32KB
    __shared__ __align__(16) short Wb[256 * 64];   // 32KB (+ G^T scratch)

    const int tid = threadIdx.x;
    const int lane = tid & 63, wid = tid >> 6;   // 4 waves
    const int lo = lane & 15, hi = lane >> 4;
    const int rb = blockIdx.x;                   // 0..511
    const int batch = rb >> 5;
    const int mb = (rb & 31) * 64;
    const size_t m0g = (size_t)rb * 64;

    {
        const int frow = tid >> 2, fq = tid & 3;
        const float* fp = F + (m0g + frow) * 256 + fq * 64;
#pragma unroll
        for (int g = 0; g < 2; ++g) {
            float4 q[8];
#pragma unroll
            for (int i = 0; i < 8; ++i)
                q[i] = reinterpret_cast<const float4*>(fp)[g * 8 + i];
#pragma unroll
            for (int j = 0; j < 4; ++j) {
                unsigned int w0 = pkbf(q[2*j].x,   q[2*j].y);
                unsigned int w1 = pkbf(q[2*j].z,   q[2*j].w);
                unsigned int w2 = pkbf(q[2*j+1].x, q[2*j+1].y);
                unsigned int w3 = pkbf(q[2*j+1].z, q[2*j+1].w);
                int slot = fq * 8 + g * 4 + j;
                int off = frow * 256 + ((slot ^ (frow & 7)) << 3);
                *reinterpret_cast<uint4*>(&Fb[off]) = make_uint4(w0, w1, w2, w3);
            }
        }
    }

    f32x4 acc[4][4];

#pragma unroll
    for (int pass = 0; pass < 2; ++pass) {
#pragma unroll
        for (int m = 0; m < 4; ++m)
#pragma unroll
            for (int n = 0; n < 4; ++n) acc[m][n] = (f32x4){0.f, 0.f, 0.f, 0.f};

        for (int kt = 0; kt < 4; ++kt) {
            const int kbase = pass * 256 + kt * 64;
#pragma unroll
            for (int it = 0; it < 8; ++it) {
                int si = it * 256 + tid;
                int row = si >> 3, slot = si & 7;
                const unsigned short* g = Wt + (size_t)row * 512 + kbase + ((slot ^ (row & 7)) << 3);
                gll16(g, Wb + (size_t)si * 8);
            }
            __syncthreads();

#pragma unroll
            for (int kk = 0; kk < 2; ++kk) {
                bf16x8 af[4], bw[4];
#pragma unroll
                for (int m = 0; m < 4; ++m) {
                    int row = m * 16 + lo;
                    int slot = kt * 8 + kk * 4 + hi;
                    af[m] = *reinterpret_cast<const bf16x8*>(&Fb[row * 256 + ((slot ^ (row & 7)) << 3)]);
                }
#pragma unroll
                for (int n = 0; n < 4; ++n) {
                    int row = wid * 64 + n * 16 + lo;
                    bw[n] = *reinterpret_cast<const bf16x8*>(&Wb[row * 64 + (((kk * 4 + hi) ^ (row & 7)) << 3)]);
                }
#pragma unroll
                for (int m = 0; m < 4; ++m)
#pragma unroll
                    for (int n = 0; n < 4; ++n)
                        acc[m][n] = __builtin_amdgcn_mfma_f32_16x16x32_bf16(af[m], bw[n], acc[m][n], 0, 0, 0);
            }
            __syncthreads();
        }

        if (pass == 0) {
            float bv[4];
#pragma unroll
            for (int n = 0; n < 4; ++n) bv[n] = bias[wid * 64 + n * 16 + lo];
            unsigned short* Hb = H + m0g * 256;
#pragma unroll
            for (int m = 0; m < 4; ++m)
#pragma unroll
                for (int n = 0; n < 4; ++n)
#pragma unroll
                    for (int j = 0; j < 4; ++j) {
                        int row = m * 16 + hi * 4 + j;
                        int col = wid * 64 + n * 16 + lo;
                        Hb[(size_t)row * 256 + col] = f2bf(acc[m][n][j] + bv[n]);
                    }
        } else {
            short* T = Wb + wid * 4096;
#pragma unroll
            for (int m = 0; m < 4; ++m)
#pragma unroll
                for (int n = 0; n < 4; ++n)
#pragma unroll
                    for (int j = 0; j < 4; ++j) {
                        int gr = m * 16 + hi * 4 + j;
                        int gc = n * 16 + lo;
                        int slot = gr >> 3, e = gr & 7;
                        T[gc * 64 + ((slot ^ (gc & 7)) << 3) + e] = f2bf(acc[m][n][j]);
                    }
            unsigned short* Gb = Gt + ((size_t)batch * 256 + wid * 64) * 2048 + mb;
#pragma unroll
            for (int i = 0; i < 8; ++i) {
                int f = i * 8 + (lane >> 3);
                int s = lane & 7;
                bf16x8 v = *reinterpret_cast<const bf16x8*>(&T[f * 64 + ((s ^ (f & 7)) << 3)]);
                *reinterpret_cast<bf16x8*>(Gb + (size_t)f * 2048 + s * 8) = v;
            }
        }
    }
}

// ---------------------------------------------------------------------------
// kMain: out = relu(H + A @ G).  BK=128 restructure (R8):
//  - bodies of BK=128 (16 total): ~1100cy of work each -> one-body prefetch
//    depth now exceeds HBM latency (~900cy) for BOTH streams.
//  - A-loads fully dense: each wave instruction reads 2 whole rows x 512B
//    (1KB, 100% sector density) instead of 16 rows x 64B.
//  - A+B double-buffered (128KB LDS); counted vmcnt(8) at the barrier keeps
//    A(t+2)x8 in flight; writeA implicitly waits vmcnt(4). No vmcnt(0) in loop.
//  - 16-slot XOR swizzle (slot ^ row&15) on 256B LDS rows: conflict-free b128.
// BM=128 BN=128, 8 waves (2x4, wave tile 64x32), grid 512 (16b x 16mt x 2nt).
// ---------------------------------------------------------------------------
__global__ __launch_bounds__(512, 2) void kmain_gemm(
    const float* __restrict__ A, const unsigned short* __restrict__ Gt,
    const unsigned short* __restrict__ H, float* __restrict__ out)
{
    __shared__ __align__(16) short Ab[2][128 * 128];   // 2 x 32KB
    __shared__ __align__(16) short Bb[2][128 * 128];   // 2 x 32KB

    const int tid = threadIdx.x;
    const int lane = tid & 63, wid = tid >> 6;
    const int wr = wid >> 2, wc = wid & 3;          // 2x4 -> wave tile 64x32
    const int lo = lane & 15, hi = lane >> 4;

    const int bid = blockIdx.x;
    const int wg = ((bid & 7) << 6) | (bid >> 3);   // bijective, 512 % 8 == 0
    const int batch = wg >> 5;
    const int mt    = (wg >> 1) & 15;
    const int nt    = wg & 1;

    const float* Abase = A + ((size_t)batch * 2048 + (size_t)mt * 128) * 2048;
    const unsigned short* Gbase = Gt + ((size_t)batch * 256 + (size_t)nt * 128) * 2048;

    f32x4 acc[4][2];
#pragma unroll
    for (int m = 0; m < 4; ++m)
#pragma unroll
        for (int n = 0; n < 2; ++n) acc[m][n] = (f32x4){0.f, 0.f, 0.f, 0.f};

    float4 qa[8];   // one body's A fragment: 8 x (2 rows x 512B dense) loads

    // dense A-load: instr i covers rows (wid*16 + 2i + lane>>5), bytes (lane&31)*16
    auto loadA = [&](int k0) {
        const float* base = Abase + k0;
#pragma unroll
        for (int i = 0; i < 8; ++i) {
            int r = (wid << 4) + (i << 1) + (lane >> 5);
            qa[i] = reinterpret_cast<const float4*>(base + (size_t)r * 2048)[lane & 31];
        }
    };
    // thread's qa[i] = row r, global k-slot g = (lane&31)>>1, half = (lane&31)&1
    auto writeA = [&](int buf) {
#pragma unroll
        for (int i = 0; i < 8; ++i) {
            int r = (wid << 4) + (i << 1) + (lane >> 5);
            int c32 = lane & 31;
            int slot = c32 >> 1, half = c32 & 1;
            int off = r * 128 + (((slot ^ (r & 15)) << 3) + half * 4);
            uint2 w;
            w.x = pkbf(qa[i].x, qa[i].y);
            w.y = pkbf(qa[i].z, qa[i].w);
            *reinterpret_cast<uint2*>(&Ab[buf][off]) = w;
        }
    };
    auto stageB = [&](int buf, int k0) {
#pragma unroll
        for (int it = 0; it < 4; ++it) {
            int si = it * 512 + tid;
            int row = si >> 4, slot = si & 15;
            const unsigned short* g = Gbase + (size_t)row * 2048 + k0 + ((slot ^ (row & 15)) << 3);
            gll16(g, &Bb[buf][(size_t)si * 8]);
        }
    };
    auto compute = [&](int buf) {
#pragma unroll
        for (int kk = 0; kk < 4; ++kk) {
            bf16x8 af[4], bfv[2];
#pragma unroll
            for (int m = 0; m < 4; ++m) {
                int row = wr * 64 + m * 16 + lo;
                int s = (kk * 4 + hi) ^ (row & 15);
                af[m] = *reinterpret_cast<const bf16x8*>(&Ab[buf][row * 128 + (s << 3)]);
            }
#pragma unroll
            for (int n = 0; n < 2; ++n) {
                int row = wc * 32 + n * 16 + lo;
                int s = (kk * 4 + hi) ^ (row & 15);
                bfv[n] = *reinterpret_cast<const bf16x8*>(&Bb[buf][row * 128 + (s << 3)]);
            }
            __builtin_amdgcn_s_setprio(1);
#pragma unroll
            for (int m = 0; m < 4; ++m)
#pragma unroll
                for (int n = 0; n < 2; ++n)
                    acc[m][n] = __builtin_amdgcn_mfma_f32_16x16x32_bf16(af[m], bfv[n], acc[m][n], 0, 0, 0);
            __builtin_amdgcn_s_setprio(0);
        }
    };

    // ---- prologue ----
    loadA(0);                       // A(0) x8
    stageB(0, 0);                   // gll(0) x4 -> Bb[0]
    writeA(0);                      // implicit vmcnt(4): A(0) done, gll(0) in flight
    loadA(128);                     // A(1) x8
    asm volatile("s_waitcnt vmcnt(8) lgkmcnt(0)" ::: "memory");  // gll(0) done; A(1) in flight
    __builtin_amdgcn_s_barrier();
    asm volatile("" ::: "memory");
    stageB(1, 128);                 // gll(1) x4 -> Bb[1] (a full body before use)

    // ---- steady bodies t = 0..13 ----
    for (int t = 0; t < 14; ++t) {
        const int cur = t & 1, nxt = cur ^ 1;
        writeA(nxt);                            // implicit vmcnt(4): A(t+1) done
        loadA((t + 2) * 128);                   // A(t+2) x8 in flight
        compute(cur);
        asm volatile("s_waitcnt vmcnt(8) lgkmcnt(0)" ::: "memory");  // gll(t+1) done; A(t+2) live
        __builtin_amdgcn_s_barrier();
        asm volatile("" ::: "memory");
        stageB(cur, (t + 2) * 128);             // gll(t+2) -> Bb[cur]
    }
    // ---- body 14 (cur=0): last A write, no more prefetch ----
    writeA(1);                                  // A(15); implicit vmcnt(4)
    compute(0);
    asm volatile("s_waitcnt vmcnt(0) lgkmcnt(0)" ::: "memory");      // drain gll(15)
    __builtin_amdgcn_s_barrier();
    asm volatile("" ::: "memory");
    // ---- body 15 (cur=1) ----
    compute(1);

    // ---- epilogue: out = relu(acc + H) ----
    const size_t rowbase = (size_t)batch * 2048 + (size_t)mt * 128;
    const unsigned short* Hb = H + rowbase * 256;
    float* obase = out + rowbase * 256;
#pragma unroll
    for (int m = 0; m < 4; ++m) {
#pragma unroll
        for (int n = 0; n < 2; ++n) {
            int col = nt * 128 + wc * 32 + n * 16 + lo;
#pragma unroll
            for (int j = 0; j < 4; ++j) {
                int row = wr * 64 + m * 16 + hi * 4 + j;
                float v = acc[m][n][j] + bf2f(Hb[(size_t)row * 256 + col]);
                obase[(size_t)row * 256 + col] = fmaxf(v, 0.f);
            }
        }
    }
}

// ---------------------------------------------------------------------------
extern "C" void kernel_launch(void* const* d_in, const int* in_sizes, int n_in,
                              void* d_out, int out_size, void* d_ws, size_t ws_size,
                              hipStream_t stream) {
    const float* features = (const float*)d_in[0];   // [16][2048][256]
    const float* A        = (const float*)d_in[1];   // [16][2048][2048]
    const float* weight   = (const float*)d_in[2];   // [512][256]
    const float* bias     = (const float*)d_in[3];   // [256]
    float* out = (float*)d_out;

    const size_t WT_B = (size_t)256 * 512 * 2;             // 256 KB
    const size_t H_B  = (size_t)32768 * 256 * 2;           // 16.78 MB
    const size_t GT_B = (size_t)16 * 256 * 2048 * 2;       // 16.78 MB
    if (ws_size < WT_B + H_B + GT_B) return;

    char* ws = (char*)d_ws;
    unsigned short* Wt = (unsigned short*)ws;
    unsigned short* H  = (unsigned short*)(ws + WT_B);
    unsigned short* Gt = (unsigned short*)(ws + WT_B + H_B);

    dim3 gW(512 / 64, 256 / 64, 1);
    transpose_cvt_kernel<<<gW, 256, 0, stream>>>(weight, Wt, nullptr, 512, 256);

    kpre_gemm<<<512, 256, 0, stream>>>(features, Wt, bias, H, Gt);

    kmain_gemm<<<512, 512, 0, stream>>>(A, Gt, H, out);
}